// Round 4
// baseline (2930.944 us; speedup 1.0000x reference)
//
#include <hip/hip_runtime.h>
#include <hip/hip_bf16.h>
#include <stdint.h>

// ---------------- constants ----------------
#define B_SZ   256
#define LSTM_N 512
#define FEAT_N 4632
#define FV_N   4608
#define CIN_N  6144
#define HALF_CIN 3072
#define ACT_N  64

// ---------------- threefry2x32 (matches jax) ----------------
__device__ __forceinline__ uint32_t rotl32(uint32_t x, int r) {
  return (x << r) | (x >> (32 - r));
}

__device__ __forceinline__ void threefry2x32(uint32_t k0, uint32_t k1,
                                             uint32_t x0, uint32_t x1,
                                             uint32_t& o0, uint32_t& o1) {
  uint32_t k2 = k0 ^ k1 ^ 0x1BD11BDAu;
  x0 += k0; x1 += k1;
  x0 += x1; x1 = rotl32(x1, 13); x1 ^= x0;
  x0 += x1; x1 = rotl32(x1, 15); x1 ^= x0;
  x0 += x1; x1 = rotl32(x1, 26); x1 ^= x0;
  x0 += x1; x1 = rotl32(x1,  6); x1 ^= x0;
  x0 += k1; x1 += k2 + 1u;
  x0 += x1; x1 = rotl32(x1, 17); x1 ^= x0;
  x0 += x1; x1 = rotl32(x1, 29); x1 ^= x0;
  x0 += x1; x1 = rotl32(x1, 16); x1 ^= x0;
  x0 += x1; x1 = rotl32(x1, 24); x1 ^= x0;
  x0 += k2; x1 += k0 + 2u;
  x0 += x1; x1 = rotl32(x1, 13); x1 ^= x0;
  x0 += x1; x1 = rotl32(x1, 15); x1 ^= x0;
  x0 += x1; x1 = rotl32(x1, 26); x1 ^= x0;
  x0 += x1; x1 = rotl32(x1,  6); x1 ^= x0;
  x0 += k0; x1 += k1 + 3u;
  x0 += x1; x1 = rotl32(x1, 17); x1 ^= x0;
  x0 += x1; x1 = rotl32(x1, 29); x1 ^= x0;
  x0 += x1; x1 = rotl32(x1, 16); x1 ^= x0;
  x0 += x1; x1 = rotl32(x1, 24); x1 ^= x0;
  x0 += k1; x1 += k2 + 4u;
  x0 += x1; x1 = rotl32(x1, 13); x1 ^= x0;
  x0 += x1; x1 = rotl32(x1, 15); x1 ^= x0;
  x0 += x1; x1 = rotl32(x1, 26); x1 ^= x0;
  x0 += x1; x1 = rotl32(x1,  6); x1 ^= x0;
  x0 += k2; x1 += k0 + 5u;
  o0 = x0; o1 = x1;
}

// ---------------- fill feats[:,4608:4632] with embeddings ----------------
__global__ void fill_embs_kernel(const int* __restrict__ lastpos,
                                 const int* __restrict__ ep,
                                 const float* __restrict__ emb_end,
                                 const float* __restrict__ emb_ep,
                                 float* __restrict__ feats) {
  int b = blockIdx.x;
  int t = threadIdx.x;
  if (t < 16) {
    feats[(size_t)b * FEAT_N + FV_N + t] = emb_end[lastpos[b] * 16 + t];
  } else if (t < 24) {
    feats[(size_t)b * FEAT_N + FV_N + 16 + (t - 16)] = emb_ep[ep[b] * 8 + (t - 16)];
  }
}

// ---------------- generic f32 GEMM with split A:  C = act(A @ W^T + b1 + b2)
#define BM 64
#define BN 64
#define BKK 16

__global__ __launch_bounds__(256) void gemm_nt_kernel(
    const float* __restrict__ A0, int lda0,
    const float* __restrict__ A1, int lda1, int ksplit,
    const float* __restrict__ W, int ldw,
    const float* __restrict__ bias1, const float* __restrict__ bias2,
    float* __restrict__ C, int ldc,
    int M, int N, int K, int do_relu) {
  __shared__ float As[BKK][BM + 4];
  __shared__ float Ws[BKK][BN + 4];
  const int tid = threadIdx.x;
  const int tx = tid & 15;
  const int ty = tid >> 4;
  const int m0 = blockIdx.x * BM;
  const int n0 = blockIdx.y * BN;
  float acc[4][4] = {};
  for (int k0 = 0; k0 < K; k0 += BKK) {
#pragma unroll
    for (int l = 0; l < 4; ++l) {
      int idx = tid + l * 256;
      int r = idx >> 4;
      int c = idx & 15;
      int gk = k0 + c;
      int gm = m0 + r;
      int gn = n0 + r;
      float av = 0.f;
      if (gm < M && gk < K) {
        av = (gk < ksplit) ? A0[(size_t)gm * lda0 + gk]
                           : A1[(size_t)gm * lda1 + (gk - ksplit)];
      }
      As[c][r] = av;
      Ws[c][r] = (gn < N && gk < K) ? W[(size_t)gn * ldw + gk] : 0.f;
    }
    __syncthreads();
#pragma unroll
    for (int kk = 0; kk < BKK; ++kk) {
      float a[4], w[4];
#pragma unroll
      for (int i = 0; i < 4; ++i) a[i] = As[kk][ty * 4 + i];
#pragma unroll
      for (int j = 0; j < 4; ++j) w[j] = Ws[kk][tx * 4 + j];
#pragma unroll
      for (int i = 0; i < 4; ++i)
#pragma unroll
        for (int j = 0; j < 4; ++j) acc[i][j] += a[i] * w[j];
    }
    __syncthreads();
  }
#pragma unroll
  for (int i = 0; i < 4; ++i) {
    int gm = m0 + ty * 4 + i;
    if (gm >= M) continue;
#pragma unroll
    for (int j = 0; j < 4; ++j) {
      int gn = n0 + tx * 4 + j;
      if (gn >= N) continue;
      float v = acc[i][j];
      if (bias1) v += bias1[gn];
      if (bias2) v += bias2[gn];
      if (do_relu) v = fmaxf(v, 0.f);
      C[(size_t)gm * ldc + gn] = v;
    }
  }
}

// ---------------- LSTM elementwise (h0 = c0 = 0) ----------------
__global__ void lstm_kernel(const float* __restrict__ gates,
                            float* __restrict__ zext) {
  int idx = blockIdx.x * blockDim.x + threadIdx.x;
  if (idx >= B_SZ * LSTM_N) return;
  int b = idx >> 9;
  int n = idx & 511;
  const float* g = gates + (size_t)b * (4 * LSTM_N);
  float gi = g[n];
  float gg = g[2 * LSTM_N + n];
  float go = g[3 * LSTM_N + n];
  float si = 1.f / (1.f + expf(-gi));
  float so = 1.f / (1.f + expf(-go));
  float c = si * tanhf(gg);
  float h = so * tanhf(c);
  zext[(size_t)b * 528 + n] = h;
}

// ---------------- softmax + gumbel-max categorical sample (one wave per row) ----------------
__global__ void sample_kernel(const float* __restrict__ logits,    // [256,64]
                              const float* __restrict__ emb_dec_k, // [64,16]
                              float* __restrict__ zext,            // write emb cols 512..527
                              int* __restrict__ act_out,           // [256]
                              float* __restrict__ logp_out,        // [256]
                              float* __restrict__ ent_out,         // [256]
                              int k, int write_emb) {
  const int b = blockIdx.x;
  const int a = threadIdx.x;  // 0..63
  float logit = logits[b * ACT_N + a];

  float m = logit;
#pragma unroll
  for (int off = 32; off; off >>= 1) m = fmaxf(m, __shfl_xor(m, off));
  float e = expf(logit - m);
  float s = e;
#pragma unroll
  for (int off = 32; off; off >>= 1) s += __shfl_xor(s, off);
  float logp = logit - m - logf(s);

  float ent = -expf(logp) * logp;
#pragma unroll
  for (int off = 32; off; off >>= 1) ent += __shfl_xor(ent, off);

  // key = fold_in(key(42), k) ; bits per jax random_bits(shape=(256,64))
  uint32_t f0, f1;
  threefry2x32(0u, 42u, 0u, (uint32_t)k, f0, f1);
  uint32_t j = (uint32_t)(b * ACT_N + a);
  uint32_t o0, o1, bits;
  if (j < 8192u) {
    threefry2x32(f0, f1, j, j + 8192u, o0, o1);
    bits = o0;
  } else {
    threefry2x32(f0, f1, j - 8192u, j, o0, o1);
    bits = o1;
  }
  const float tiny = 1.17549435e-38f;
  float fu = __uint_as_float((bits >> 9) | 0x3f800000u) - 1.0f;
  float u = fmaxf(tiny, fu * (1.0f - tiny) + tiny);
  float gum = -logf(-logf(u));
  float pert = logit + gum;

  // argmax with first-index tie-break
  float bv = pert;
  int bi = a;
#pragma unroll
  for (int off = 32; off; off >>= 1) {
    float ov = __shfl_xor(bv, off);
    int oi = __shfl_xor(bi, off);
    if (ov > bv || (ov == bv && oi < bi)) { bv = ov; bi = oi; }
  }
  int act = bi;
  float lp_sel = __shfl(logp, act);

  if (a == 0) {
    act_out[b] = act;
    logp_out[b] = lp_sel;
    ent_out[b] = ent;
  }
  if (write_emb && a < 16) {
    zext[(size_t)b * 528 + 512 + a] = emb_dec_k[act * 16 + a];
  }
}

// ---------------- finalize: pack outputs as FLOAT32 ----------------
// layout: action[256*4] | entropy[1] | logp[256]   (1281 floats)
__global__ void finalize_kernel(const int* __restrict__ act,      // [4][256]
                                const float* __restrict__ logp_k, // [4][256]
                                const float* __restrict__ ent,    // [4][256]
                                float* __restrict__ out) {
  int t = threadIdx.x;  // 0..255
#pragma unroll
  for (int k = 0; k < 4; ++k)
    out[t * 4 + k] = (float)act[k * 256 + t];
  float lp = 0.f;
#pragma unroll
  for (int k = 0; k < 4; ++k) lp += logp_k[k * 256 + t];
  out[1025 + t] = lp;
  if (t == 0) {
    float e = 0.f;
    for (int i = 0; i < 1024; ++i) e += ent[i];
    out[1024] = e;
  }
}

// ---------------- host launch ----------------
extern "C" void kernel_launch(void* const* d_in, const int* in_sizes, int n_in,
                              void* d_out, int out_size, void* d_ws, size_t ws_size,
                              hipStream_t stream) {
  float* out = (float*)d_out;
  char* out_bytes = (char*)d_out;

  // diagnostic channel: memset the 4 bytes of f32 out[1024] (entropy slot).
  // 0x42424242 = 48.56f -> visible as err ~4209 (vs 4256 for untouched-0).
  auto sentinel = [&](int code) {
    hipMemsetAsync(out_bytes + 4096, code, 4, stream);
  };

  // ---- validate marshalling assumptions ----
  if (n_in < 25 || in_sizes[0] != B_SZ * 3 * 32 * 32 ||
      in_sizes[4] != FV_N * CIN_N || in_sizes[23] != LSTM_N * 528 ||
      in_sizes[9] <= 0 || in_sizes[9] > 8192 ||
      in_sizes[11] <= 0 || in_sizes[11] > 8192) {
    sentinel(0x42);
    return;
  }

  const float* actual = (const float*)d_in[0];
  const float* object = (const float*)d_in[1];
  const int* lastpos  = (const int*)d_in[2];
  const int* ep       = (const int*)d_in[3];
  const float* Wfe    = (const float*)d_in[4];
  const float* bfe    = (const float*)d_in[5];
  const float* emb_end= (const float*)d_in[6];
  const float* emb_ep = (const float*)d_in[7];
  const float* W1     = (const float*)d_in[8];
  const float* b1     = (const float*)d_in[9];
  const float* W2     = (const float*)d_in[10];
  const float* b2     = (const float*)d_in[11];
  const float* W3     = (const float*)d_in[12];
  const float* b3     = (const float*)d_in[13];
  const float* W_ih   = (const float*)d_in[14];
  const float* b_ih   = (const float*)d_in[16];
  const float* b_hh   = (const float*)d_in[17];
  const float* Wd1    = (const float*)d_in[18];
  const float* bd1    = (const float*)d_in[19];
  const float* Wd2    = (const float*)d_in[20];
  const float* bd2    = (const float*)d_in[21];
  const float* embdec = (const float*)d_in[22];
  const float* Wout   = (const float*)d_in[23];
  const float* bout   = (const float*)d_in[24];

  const int H1 = in_sizes[9];   // len(b1)
  const int H2 = in_sizes[11];  // len(b2)

  // ---- workspace layout (~7.04 MB peak) ----
  const size_t r2_rows = (size_t)((H1 > 1056) ? H1 : 1056);
  const size_t need_floats = 3072 + (size_t)B_SZ * FEAT_N + (size_t)B_SZ * r2_rows;
  if (ws_size < need_floats * 4) {
    sentinel(0x43);
    return;
  }
  float* ws = (float*)d_ws;
  float* logpk = ws;                      // 1024
  float* entk  = ws + 1024;               // 1024
  int*   actk  = (int*)(ws + 2048);       // 1024
  float* R1 = ws + 3072;
  float* R2 = R1 + (size_t)B_SZ * FEAT_N;

  float* feats = R1;                 // live: GEMM1..GEMM2
  float* h1    = R2;                 // live: GEMM2..GEMM3
  float* h2    = R1;                 // live: GEMM3..GEMM4
  float* h3    = R2;                 // live: GEMM4..GEMM5
  float* gates = R1;                 // live: GEMM5..lstm
  float* zextA = R2;                 // live: lstm..decoder
  float* zextB = R2 + (size_t)B_SZ * 528;
  float* hm    = R1;                 // decoder scratch
  float* logit = R1 + (size_t)B_SZ * 256;

  auto gemm = [&](const float* A0, int lda0, const float* A1, int lda1, int ksplit,
                  const float* W, int ldw, const float* bb1, const float* bb2,
                  float* C, int ldc, int M, int N, int K, int relu) {
    dim3 g((M + BM - 1) / BM, (N + BN - 1) / BN);
    gemm_nt_kernel<<<g, dim3(256), 0, stream>>>(
        A0, lda0, A1, lda1, ksplit, W, ldw, bb1, bb2, C, ldc, M, N, K, relu);
  };

  // 1. fv = relu(concat(actual,objective) @ Wfe^T + bfe) -> feats[:, :4608]
  gemm(actual, HALF_CIN, object, HALF_CIN, HALF_CIN,
       Wfe, CIN_N, bfe, nullptr, feats, FEAT_N, B_SZ, FV_N, CIN_N, 1);
  // 2. embeddings -> feats[:, 4608:]
  fill_embs_kernel<<<dim3(B_SZ), dim3(64), 0, stream>>>(
      lastpos, ep, emb_end, emb_ep, feats);
  // 3. h1 = relu(feats @ W1^T + b1)
  gemm(feats, FEAT_N, feats, 0, FEAT_N, W1, FEAT_N, b1, nullptr,
       h1, H1, B_SZ, H1, FEAT_N, 1);
  // 4. h2 = relu(h1 @ W2^T + b2)
  gemm(h1, H1, h1, 0, H1, W2, H1, b2, nullptr, h2, H2, B_SZ, H2, H1, 1);
  // 5. h3 = relu(h2 @ W3^T + b3)
  gemm(h2, H2, h2, 0, H2, W3, H2, b3, nullptr, h3, LSTM_N, B_SZ, LSTM_N, H2, 1);
  // 6. gates = h3 @ W_ih^T + b_ih + b_hh
  gemm(h3, LSTM_N, h3, 0, LSTM_N, W_ih, LSTM_N, b_ih, b_hh,
       gates, 4 * LSTM_N, B_SZ, 4 * LSTM_N, LSTM_N, 0);
  // 7. LSTM elementwise -> zextA[:, :512]
  lstm_kernel<<<dim3((B_SZ * LSTM_N + 255) / 256), dim3(256), 0, stream>>>(
      gates, zextA);

  // 8. autoregressive decoder
  float* zcur = zextA;
  float* znxt = zextB;
  for (int k = 0; k < 4; ++k) {
    const float* Wd1k = Wd1 + (size_t)k * 256 * LSTM_N;
    const float* bd1k = bd1 + (size_t)k * 256;
    const float* Wd2k = Wd2 + (size_t)k * ACT_N * 256;
    const float* bd2k = bd2 + (size_t)k * ACT_N;
    const float* embk = embdec + (size_t)k * ACT_N * 16;
    // hm = relu(z @ Wd1[k]^T + bd1[k])   (z = zcur[:, :512])
    gemm(zcur, 528, zcur, 0, LSTM_N, Wd1k, LSTM_N, bd1k, nullptr,
         hm, 256, B_SZ, 256, LSTM_N, 1);
    // logits = hm @ Wd2[k]^T + bd2[k]
    gemm(hm, 256, hm, 0, 256, Wd2k, 256, bd2k, nullptr,
         logit, ACT_N, B_SZ, ACT_N, 256, 0);
    // sample + entropy + logp (+ write emb into zcur cols 512:528)
    sample_kernel<<<dim3(B_SZ), dim3(64), 0, stream>>>(
        logit, embk, zcur, actk + k * B_SZ, logpk + k * B_SZ,
        entk + k * B_SZ, k, (k < 3) ? 1 : 0);
    if (k < 3) {
      // z' = relu([z, emb] @ Wout^T + bout) -> znxt[:, :512]
      gemm(zcur, 528, zcur, 0, 528, Wout, 528, bout, nullptr,
           znxt, 528, B_SZ, LSTM_N, 528, 1);
      float* t = zcur; zcur = znxt; znxt = t;
    }
  }

  // 9. pack outputs (f32): action[1024] | entropy[1] | logp[256]
  finalize_kernel<<<dim3(1), dim3(256), 0, stream>>>(actk, logpk, entk, out);
}

// Round 5
// 784.016 us; speedup vs baseline: 3.7384x; 3.7384x over previous
//
#include <hip/hip_runtime.h>
#include <hip/hip_bf16.h>
#include <stdint.h>

// ---------------- constants ----------------
#define B_SZ   256
#define LSTM_N 512
#define FEAT_N 4632
#define FV_N   4608
#define CIN_N  6144
#define HALF_CIN 3072
#define ACT_N  64

// padded strides for intermediates (16B-aligned rows)
#define LD_H1  2224
#define LD_H2  1068

typedef __attribute__((ext_vector_type(8))) short bf16x8;
typedef __attribute__((ext_vector_type(4))) float f32x4;

__device__ __forceinline__ short f2bf(float f) {
  uint32_t u = __float_as_uint(f);
  u += 0x7FFFu + ((u >> 16) & 1u);
  return (short)(u >> 16);
}

// ---------------- threefry2x32 (matches jax) ----------------
__device__ __forceinline__ uint32_t rotl32(uint32_t x, int r) {
  return (x << r) | (x >> (32 - r));
}

__device__ __forceinline__ void threefry2x32(uint32_t k0, uint32_t k1,
                                             uint32_t x0, uint32_t x1,
                                             uint32_t& o0, uint32_t& o1) {
  uint32_t k2 = k0 ^ k1 ^ 0x1BD11BDAu;
  x0 += k0; x1 += k1;
  x0 += x1; x1 = rotl32(x1, 13); x1 ^= x0;
  x0 += x1; x1 = rotl32(x1, 15); x1 ^= x0;
  x0 += x1; x1 = rotl32(x1, 26); x1 ^= x0;
  x0 += x1; x1 = rotl32(x1,  6); x1 ^= x0;
  x0 += k1; x1 += k2 + 1u;
  x0 += x1; x1 = rotl32(x1, 17); x1 ^= x0;
  x0 += x1; x1 = rotl32(x1, 29); x1 ^= x0;
  x0 += x1; x1 = rotl32(x1, 16); x1 ^= x0;
  x0 += x1; x1 = rotl32(x1, 24); x1 ^= x0;
  x0 += k2; x1 += k0 + 2u;
  x0 += x1; x1 = rotl32(x1, 13); x1 ^= x0;
  x0 += x1; x1 = rotl32(x1, 15); x1 ^= x0;
  x0 += x1; x1 = rotl32(x1, 26); x1 ^= x0;
  x0 += x1; x1 = rotl32(x1,  6); x1 ^= x0;
  x0 += k0; x1 += k1 + 3u;
  x0 += x1; x1 = rotl32(x1, 17); x1 ^= x0;
  x0 += x1; x1 = rotl32(x1, 29); x1 ^= x0;
  x0 += x1; x1 = rotl32(x1, 16); x1 ^= x0;
  x0 += x1; x1 = rotl32(x1, 24); x1 ^= x0;
  x0 += k1; x1 += k2 + 4u;
  x0 += x1; x1 = rotl32(x1, 13); x1 ^= x0;
  x0 += x1; x1 = rotl32(x1, 15); x1 ^= x0;
  x0 += x1; x1 = rotl32(x1, 26); x1 ^= x0;
  x0 += x1; x1 = rotl32(x1,  6); x1 ^= x0;
  x0 += k2; x1 += k0 + 5u;
  o0 = x0; o1 = x1;
}

// ---------------- fill feats[:,4608:4632] with embeddings ----------------
__global__ void fill_embs_kernel(const int* __restrict__ lastpos,
                                 const int* __restrict__ ep,
                                 const float* __restrict__ emb_end,
                                 const float* __restrict__ emb_ep,
                                 float* __restrict__ feats) {
  int b = blockIdx.x;
  int t = threadIdx.x;
  if (t < 16) {
    feats[(size_t)b * FEAT_N + FV_N + t] = emb_end[lastpos[b] * 16 + t];
  } else if (t < 24) {
    feats[(size_t)b * FEAT_N + FV_N + 16 + (t - 16)] = emb_ep[ep[b] * 8 + (t - 16)];
  }
}

// ---------------- bf16 MFMA GEMM:  C = act(A @ W^T + b1 + b2) ----------------
// M fixed = 256. Block tile 64m x 64n, 4 waves (wave w = m rows [16w,16w+16)).
// W tile (64n x 64k) staged f32->bf16 into double-buffered LDS (row stride 72).
// A read global->reg, converted in-reg. A split at ksplit (8-aligned) for concat.
#define LDSW 72

__global__ __launch_bounds__(256) void gemm_mfma_kernel(
    const float* __restrict__ A0, int lda0,
    const float* __restrict__ A1, int lda1, int ksplit,
    const float* __restrict__ W, int ldw,
    const float* __restrict__ bias1, const float* __restrict__ bias2,
    float* __restrict__ C, int ldc,
    int N, int K, int do_relu) {
  __shared__ short Wlds[2][64 * LDSW];

  const int tid = threadIdx.x;
  const int w = tid >> 6;        // wave 0..3
  const int l = tid & 63;        // lane
  const int l15 = l & 15;
  const int lg = l >> 4;         // 0..3
  const int m0 = blockIdx.x * 64;
  const int n0 = blockIdx.y * 64;

  const bool w_fast_ld = ((ldw & 3) == 0);

  f32x4 acc[4];
#pragma unroll
  for (int t = 0; t < 4; ++t) acc[t] = (f32x4){0.f, 0.f, 0.f, 0.f};

  float4 wreg[4];

  // ---- load W tile (k0..k0+64) into regs (per wave: rows w*16..w*16+16) ----
  auto loadW = [&](int k0) {
    const bool fast = w_fast_ld && (k0 + 64 <= K);
#pragma unroll
    for (int t = 0; t < 4; ++t) {
      int r = (w << 4) + (t << 2) + lg;
      int gn = n0 + r; if (gn >= N) gn = N - 1;
      int gk = k0 + (l15 << 2);
      const float* p = W + (size_t)gn * ldw + gk;
      if (fast) {
        wreg[t] = *(const float4*)p;
      } else {
        float4 v = {0.f, 0.f, 0.f, 0.f};
        if (gk + 0 < K) v.x = p[0];
        if (gk + 1 < K) v.y = p[1];
        if (gk + 2 < K) v.z = p[2];
        if (gk + 3 < K) v.w = p[3];
        wreg[t] = v;
      }
    }
  };
  // ---- convert + store W tile into LDS buf ----
  auto storeW = [&](int buf) {
#pragma unroll
    for (int t = 0; t < 4; ++t) {
      int r = (w << 4) + (t << 2) + lg;
      short4 s;
      s.x = f2bf(wreg[t].x); s.y = f2bf(wreg[t].y);
      s.z = f2bf(wreg[t].z); s.w = f2bf(wreg[t].w);
      *(short4*)&Wlds[buf][r * LDSW + (l15 << 2)] = s;
    }
  };
  // ---- load A fragment (8 f32 -> bf16x8) for k-offset kb ----
  auto loadA = [&](int kb, bf16x8& f) {
    int m = m0 + (w << 4) + l15;
    int kk = kb + (lg << 3);
    const float* base; int kloc; int lda;
    if (kk < ksplit) { base = A0; kloc = kk; lda = lda0; }
    else             { base = A1; kloc = kk - ksplit; lda = lda1; }
    const float* p = base + (size_t)m * lda + kloc;
    float va[8];
    if (kk + 8 <= K) {
      float4 u = ((const float4*)p)[0];
      float4 v = ((const float4*)p)[1];
      va[0]=u.x; va[1]=u.y; va[2]=u.z; va[3]=u.w;
      va[4]=v.x; va[5]=v.y; va[6]=v.z; va[7]=v.w;
    } else {
#pragma unroll
      for (int j = 0; j < 8; ++j) va[j] = (kk + j < K) ? p[j] : 0.f;
    }
#pragma unroll
    for (int j = 0; j < 8; ++j) f[j] = f2bf(va[j]);
  };

  const int nk = (K + 63) >> 6;

  loadW(0);
  storeW(0);
  __syncthreads();

  for (int kt = 0; kt < nk; ++kt) {
    const int cur = kt & 1;
    const int k0 = kt << 6;
    // A fragments for this k-step (issued first so compute waits only on them)
    bf16x8 a0, a1;
    loadA(k0, a0);
    loadA(k0 + 32, a1);
    // prefetch next W tile into regs (latency hidden under compute)
    if (kt + 1 < nk) loadW(k0 + 64);
    // compute from LDS buf[cur]
#pragma unroll
    for (int t = 0; t < 4; ++t) {
      int n = (t << 4) + l15;
      bf16x8 b0 = *(const bf16x8*)&Wlds[cur][n * LDSW + (lg << 3)];
      acc[t] = __builtin_amdgcn_mfma_f32_16x16x32_bf16(a0, b0, acc[t], 0, 0, 0);
      bf16x8 b1 = *(const bf16x8*)&Wlds[cur][n * LDSW + 32 + (lg << 3)];
      acc[t] = __builtin_amdgcn_mfma_f32_16x16x32_bf16(a1, b1, acc[t], 0, 0, 0);
    }
    if (kt + 1 < nk) {
      __syncthreads();           // everyone done reading buf[cur]
      storeW(cur ^ 1);           // (compiler waits vmcnt for wreg here)
      __syncthreads();           // buf[cur^1] ready
    }
  }

  // ---- epilogue: bias + relu, f32 store ----
#pragma unroll
  for (int t = 0; t < 4; ++t) {
    int gn = n0 + (t << 4) + l15;
    if (gn >= N) continue;
    float bsum = 0.f;
    if (bias1) bsum += bias1[gn];
    if (bias2) bsum += bias2[gn];
#pragma unroll
    for (int r = 0; r < 4; ++r) {
      int gm = m0 + (w << 4) + (lg << 2) + r;
      float v = acc[t][r] + bsum;
      if (do_relu) v = fmaxf(v, 0.f);
      C[(size_t)gm * ldc + gn] = v;
    }
  }
}

// ---------------- LSTM elementwise (h0 = c0 = 0) ----------------
__global__ void lstm_kernel(const float* __restrict__ gates,
                            float* __restrict__ zext) {
  int idx = blockIdx.x * blockDim.x + threadIdx.x;
  if (idx >= B_SZ * LSTM_N) return;
  int b = idx >> 9;
  int n = idx & 511;
  const float* g = gates + (size_t)b * (4 * LSTM_N);
  float gi = g[n];
  float gg = g[2 * LSTM_N + n];
  float go = g[3 * LSTM_N + n];
  float si = 1.f / (1.f + expf(-gi));
  float so = 1.f / (1.f + expf(-go));
  float c = si * tanhf(gg);
  float h = so * tanhf(c);
  zext[(size_t)b * 528 + n] = h;
}

// ---------------- softmax + gumbel-max categorical sample (one wave per row) ----------------
__global__ void sample_kernel(const float* __restrict__ logits,    // [256,64]
                              const float* __restrict__ emb_dec_k, // [64,16]
                              float* __restrict__ zext,            // write emb cols 512..527
                              int* __restrict__ act_out,           // [256]
                              float* __restrict__ logp_out,        // [256]
                              float* __restrict__ ent_out,         // [256]
                              int k, int write_emb) {
  const int b = blockIdx.x;
  const int a = threadIdx.x;  // 0..63
  float logit = logits[b * ACT_N + a];

  float m = logit;
#pragma unroll
  for (int off = 32; off; off >>= 1) m = fmaxf(m, __shfl_xor(m, off));
  float e = expf(logit - m);
  float s = e;
#pragma unroll
  for (int off = 32; off; off >>= 1) s += __shfl_xor(s, off);
  float logp = logit - m - logf(s);

  float ent = -expf(logp) * logp;
#pragma unroll
  for (int off = 32; off; off >>= 1) ent += __shfl_xor(ent, off);

  uint32_t f0, f1;
  threefry2x32(0u, 42u, 0u, (uint32_t)k, f0, f1);
  uint32_t j = (uint32_t)(b * ACT_N + a);
  uint32_t o0, o1, bits;
  if (j < 8192u) {
    threefry2x32(f0, f1, j, j + 8192u, o0, o1);
    bits = o0;
  } else {
    threefry2x32(f0, f1, j - 8192u, j, o0, o1);
    bits = o1;
  }
  const float tiny = 1.17549435e-38f;
  float fu = __uint_as_float((bits >> 9) | 0x3f800000u) - 1.0f;
  float u = fmaxf(tiny, fu * (1.0f - tiny) + tiny);
  float gum = -logf(-logf(u));
  float pert = logit + gum;

  float bv = pert;
  int bi = a;
#pragma unroll
  for (int off = 32; off; off >>= 1) {
    float ov = __shfl_xor(bv, off);
    int oi = __shfl_xor(bi, off);
    if (ov > bv || (ov == bv && oi < bi)) { bv = ov; bi = oi; }
  }
  int act = bi;
  float lp_sel = __shfl(logp, act);

  if (a == 0) {
    act_out[b] = act;
    logp_out[b] = lp_sel;
    ent_out[b] = ent;
  }
  if (write_emb && a < 16) {
    zext[(size_t)b * 528 + 512 + a] = emb_dec_k[act * 16 + a];
  }
}

// ---------------- finalize: pack outputs as FLOAT32 ----------------
// layout: action[256*4] | entropy[1] | logp[256]   (1281 floats)
__global__ void finalize_kernel(const int* __restrict__ act,      // [4][256]
                                const float* __restrict__ logp_k, // [4][256]
                                const float* __restrict__ ent,    // [4][256]
                                float* __restrict__ out) {
  int t = threadIdx.x;  // 0..255
#pragma unroll
  for (int k = 0; k < 4; ++k)
    out[t * 4 + k] = (float)act[k * 256 + t];
  float lp = 0.f;
#pragma unroll
  for (int k = 0; k < 4; ++k) lp += logp_k[k * 256 + t];
  out[1025 + t] = lp;
  if (t == 0) {
    float e = 0.f;
    for (int i = 0; i < 1024; ++i) e += ent[i];
    out[1024] = e;
  }
}

// ---------------- host launch ----------------
extern "C" void kernel_launch(void* const* d_in, const int* in_sizes, int n_in,
                              void* d_out, int out_size, void* d_ws, size_t ws_size,
                              hipStream_t stream) {
  float* out = (float*)d_out;
  char* out_bytes = (char*)d_out;

  auto sentinel = [&](int code) {
    hipMemsetAsync(out_bytes + 4096, code, 4, stream);
  };

  if (n_in < 25 || in_sizes[0] != B_SZ * 3 * 32 * 32 ||
      in_sizes[4] != FV_N * CIN_N || in_sizes[23] != LSTM_N * 528 ||
      in_sizes[9] <= 0 || in_sizes[9] > 8192 ||
      in_sizes[11] <= 0 || in_sizes[11] > 8192) {
    sentinel(0x42);
    return;
  }

  const float* actual = (const float*)d_in[0];
  const float* object = (const float*)d_in[1];
  const int* lastpos  = (const int*)d_in[2];
  const int* ep       = (const int*)d_in[3];
  const float* Wfe    = (const float*)d_in[4];
  const float* bfe    = (const float*)d_in[5];
  const float* emb_end= (const float*)d_in[6];
  const float* emb_ep = (const float*)d_in[7];
  const float* W1     = (const float*)d_in[8];
  const float* b1     = (const float*)d_in[9];
  const float* W2     = (const float*)d_in[10];
  const float* b2     = (const float*)d_in[11];
  const float* W3     = (const float*)d_in[12];
  const float* b3     = (const float*)d_in[13];
  const float* W_ih   = (const float*)d_in[14];
  const float* b_ih   = (const float*)d_in[16];
  const float* b_hh   = (const float*)d_in[17];
  const float* Wd1    = (const float*)d_in[18];
  const float* bd1    = (const float*)d_in[19];
  const float* Wd2    = (const float*)d_in[20];
  const float* bd2    = (const float*)d_in[21];
  const float* embdec = (const float*)d_in[22];
  const float* Wout   = (const float*)d_in[23];
  const float* bout   = (const float*)d_in[24];

  const int H1 = in_sizes[9];   // 2223
  const int H2 = in_sizes[11];  // 1067

  // ---- workspace ----
  const size_t r2_rows = (size_t)((LD_H1 > 1056) ? LD_H1 : 1056);
  const size_t need_floats = 3072 + (size_t)B_SZ * FEAT_N + (size_t)B_SZ * r2_rows;
  if (ws_size < need_floats * 4) {
    sentinel(0x43);
    return;
  }
  float* ws = (float*)d_ws;
  float* logpk = ws;                      // 1024
  float* entk  = ws + 1024;               // 1024
  int*   actk  = (int*)(ws + 2048);       // 1024
  float* R1 = ws + 3072;
  float* R2 = R1 + (size_t)B_SZ * FEAT_N;

  float* feats = R1;                 // [256][4632]
  float* h1    = R2;                 // [256][LD_H1]
  float* h2    = R1;                 // [256][LD_H2]
  float* h3    = R2;                 // [256][512]
  float* gates = R1;                 // [256][2048]
  float* zextA = R2;                 // [256][528]
  float* zextB = R2 + (size_t)B_SZ * 528;
  float* hm    = R1;                 // [256][256]
  float* logit = R1 + (size_t)B_SZ * 256;  // [256][64]

  auto gemm = [&](const float* A0, int lda0, const float* A1, int lda1, int ksplit,
                  const float* W, int ldw, const float* bb1, const float* bb2,
                  float* C, int ldc, int N, int K, int relu) {
    dim3 g(4, (N + 63) / 64);
    gemm_mfma_kernel<<<g, dim3(256), 0, stream>>>(
        A0, lda0, A1, lda1, ksplit, W, ldw, bb1, bb2, C, ldc, N, K, relu);
  };

  // 1. fv = relu(concat(actual,objective) @ Wfe^T + bfe) -> feats[:, :4608]
  gemm(actual, HALF_CIN, object, HALF_CIN, HALF_CIN,
       Wfe, CIN_N, bfe, nullptr, feats, FEAT_N, FV_N, CIN_N, 1);
  // 2. embeddings -> feats[:, 4608:]
  fill_embs_kernel<<<dim3(B_SZ), dim3(64), 0, stream>>>(
      lastpos, ep, emb_end, emb_ep, feats);
  // 3. h1 = relu(feats @ W1^T + b1)
  gemm(feats, FEAT_N, feats, 0, FEAT_N, W1, FEAT_N, b1, nullptr,
       h1, LD_H1, H1, FEAT_N, 1);
  // 4. h2 = relu(h1 @ W2^T + b2)
  gemm(h1, LD_H1, h1, 0, H1, W2, H1, b2, nullptr, h2, LD_H2, H2, H1, 1);
  // 5. h3 = relu(h2 @ W3^T + b3)
  gemm(h2, LD_H2, h2, 0, H2, W3, H2, b3, nullptr, h3, LSTM_N, LSTM_N, H2, 1);
  // 6. gates = h3 @ W_ih^T + b_ih + b_hh
  gemm(h3, LSTM_N, h3, 0, LSTM_N, W_ih, LSTM_N, b_ih, b_hh,
       gates, 4 * LSTM_N, 4 * LSTM_N, LSTM_N, 0);
  // 7. LSTM elementwise -> zextA[:, :512]
  lstm_kernel<<<dim3((B_SZ * LSTM_N + 255) / 256), dim3(256), 0, stream>>>(
      gates, zextA);

  // 8. autoregressive decoder
  float* zcur = zextA;
  float* znxt = zextB;
  for (int k = 0; k < 4; ++k) {
    const float* Wd1k = Wd1 + (size_t)k * 256 * LSTM_N;
    const float* bd1k = bd1 + (size_t)k * 256;
    const float* Wd2k = Wd2 + (size_t)k * ACT_N * 256;
    const float* bd2k = bd2 + (size_t)k * ACT_N;
    const float* embk = embdec + (size_t)k * ACT_N * 16;
    // hm = relu(z @ Wd1[k]^T + bd1[k])
    gemm(zcur, 528, zcur, 0, LSTM_N, Wd1k, LSTM_N, bd1k, nullptr,
         hm, 256, 256, LSTM_N, 1);
    // logits = hm @ Wd2[k]^T + bd2[k]
    gemm(hm, 256, hm, 0, 256, Wd2k, 256, bd2k, nullptr,
         logit, ACT_N, ACT_N, 256, 0);
    // sample + entropy + logp (+ write emb into zcur cols 512:528)
    sample_kernel<<<dim3(B_SZ), dim3(64), 0, stream>>>(
        logit, embk, zcur, actk + k * B_SZ, logpk + k * B_SZ,
        entk + k * B_SZ, k, (k < 3) ? 1 : 0);
    if (k < 3) {
      // z' = relu([z, emb] @ Wout^T + bout)
      gemm(zcur, 528, zcur, 0, 528, Wout, 528, bout, nullptr,
           znxt, 528, LSTM_N, 528, 1);
      float* t = zcur; zcur = znxt; znxt = t;
    }
  }

  // 9. pack outputs (f32): action[1024] | entropy[1] | logp[256]
  finalize_kernel<<<dim3(1), dim3(256), 0, stream>>>(actk, logpk, entk, out);
}

// Round 6
// 470.526 us; speedup vs baseline: 6.2291x; 1.6663x over previous
//
#include <hip/hip_runtime.h>
#include <hip/hip_bf16.h>
#include <stdint.h>

// ---------------- constants ----------------
#define B_SZ   256
#define LSTM_N 512
#define FEAT_N 4632
#define FV_N   4608
#define CIN_N  6144
#define HALF_CIN 3072
#define ACT_N  64

// padded strides for intermediates (16B-aligned rows)
#define LD_H1  2224
#define LD_H2  1068

#define LDSW 72   // LDS row stride (shorts) for 64-wide k tile

typedef __attribute__((ext_vector_type(8))) short bf16x8;
typedef __attribute__((ext_vector_type(4))) float f32x4;

__device__ __forceinline__ short f2bf(float f) {
  uint32_t u = __float_as_uint(f);
  u += 0x7FFFu + ((u >> 16) & 1u);
  return (short)(u >> 16);
}

// ---------------- threefry2x32 (matches jax) ----------------
__device__ __forceinline__ uint32_t rotl32(uint32_t x, int r) {
  return (x << r) | (x >> (32 - r));
}

__device__ __forceinline__ void threefry2x32(uint32_t k0, uint32_t k1,
                                             uint32_t x0, uint32_t x1,
                                             uint32_t& o0, uint32_t& o1) {
  uint32_t k2 = k0 ^ k1 ^ 0x1BD11BDAu;
  x0 += k0; x1 += k1;
  x0 += x1; x1 = rotl32(x1, 13); x1 ^= x0;
  x0 += x1; x1 = rotl32(x1, 15); x1 ^= x0;
  x0 += x1; x1 = rotl32(x1, 26); x1 ^= x0;
  x0 += x1; x1 = rotl32(x1,  6); x1 ^= x0;
  x0 += k1; x1 += k2 + 1u;
  x0 += x1; x1 = rotl32(x1, 17); x1 ^= x0;
  x0 += x1; x1 = rotl32(x1, 29); x1 ^= x0;
  x0 += x1; x1 = rotl32(x1, 16); x1 ^= x0;
  x0 += x1; x1 = rotl32(x1, 24); x1 ^= x0;
  x0 += k2; x1 += k0 + 2u;
  x0 += x1; x1 = rotl32(x1, 13); x1 ^= x0;
  x0 += x1; x1 = rotl32(x1, 15); x1 ^= x0;
  x0 += x1; x1 = rotl32(x1, 26); x1 ^= x0;
  x0 += x1; x1 = rotl32(x1,  6); x1 ^= x0;
  x0 += k0; x1 += k1 + 3u;
  x0 += x1; x1 = rotl32(x1, 17); x1 ^= x0;
  x0 += x1; x1 = rotl32(x1, 29); x1 ^= x0;
  x0 += x1; x1 = rotl32(x1, 16); x1 ^= x0;
  x0 += x1; x1 = rotl32(x1, 24); x1 ^= x0;
  x0 += k1; x1 += k2 + 4u;
  x0 += x1; x1 = rotl32(x1, 13); x1 ^= x0;
  x0 += x1; x1 = rotl32(x1, 15); x1 ^= x0;
  x0 += x1; x1 = rotl32(x1, 26); x1 ^= x0;
  x0 += x1; x1 = rotl32(x1,  6); x1 ^= x0;
  x0 += k2; x1 += k0 + 5u;
  o0 = x0; o1 = x1;
}

// ---------------- fill feats[:,4608:4632] with embeddings ----------------
__global__ void fill_embs_kernel(const int* __restrict__ lastpos,
                                 const int* __restrict__ ep,
                                 const float* __restrict__ emb_end,
                                 const float* __restrict__ emb_ep,
                                 float* __restrict__ feats) {
  int b = blockIdx.x;
  int t = threadIdx.x;
  if (t < 16) {
    feats[(size_t)b * FEAT_N + FV_N + t] = emb_end[lastpos[b] * 16 + t];
  } else if (t < 24) {
    feats[(size_t)b * FEAT_N + FV_N + 16 + (t - 16)] = emb_ep[ep[b] * 8 + (t - 16)];
  }
}

// ---------------- bf16 MFMA GEMM v2 ----------------
// C[256,N] = act(A[256,K] @ W[N,K]^T + b1 + b2)
// M unsplit (W read ONCE). Block: 512 threads (8 waves), tile 256m x 64n.
// Wave w owns m rows [32w, 32w+32): 2 m-frags x 4 n-frags of 16x16.
// K split into `nchunks` chunks of kc (64-mult); chunk ks -> partial slab P[ks].
// W tile (64n x 64k) staged f32->bf16 into double-buffered LDS, depth-2 reg prefetch.
// A loaded global->reg f32 (double-buffered), converted in-reg.
__global__ __launch_bounds__(512) void gemm2_kernel(
    const float* __restrict__ A0, int lda0,
    const float* __restrict__ A1, int lda1, int ksplit,
    const float* __restrict__ W, int ldw,
    const float* __restrict__ bias1, const float* __restrict__ bias2,
    float* __restrict__ C, int ldc,
    float* __restrict__ P, int Np,
    int N, int K, int do_relu, int kc, int nchunks) {
  __shared__ short Wlds[2][64 * LDSW];

  const int tid = threadIdx.x;
  const int w = tid >> 6;
  const int l = tid & 63;
  const int l15 = l & 15;
  const int lg = l >> 4;
  const int n0 = blockIdx.x * 64;
  const int ks = blockIdx.y;

  const int kbeg = ks * kc;
  const int kend = (kbeg + kc < K) ? (kbeg + kc) : K;
  const int nk = (kend - kbeg + 63) >> 6;

  const bool wfast = ((ldw & 3) == 0);

  // W reg buffers (depth 2)
  float4 wr[2][2];
  // A reg buffers (f32, next step) + current bf16
  float4 an[8];
  bf16x8 ac[2][2];

  f32x4 acc[2][4];
#pragma unroll
  for (int i = 0; i < 2; ++i)
#pragma unroll
    for (int j = 0; j < 4; ++j) acc[i][j] = (f32x4){0.f, 0.f, 0.f, 0.f};

  const int wrow = tid >> 3;     // 0..63 (staging row)
  const int wq   = tid & 7;      // 0..7  (staging k-quad)

  auto loadW = [&](float4* dst, int k0) {
    int gn = n0 + wrow; if (gn >= N) gn = N - 1;
    int gk = k0 + (wq << 3);
    const float* p = W + (size_t)gn * ldw + gk;
    if (wfast && (k0 + 64 <= K)) {
      dst[0] = ((const float4*)p)[0];
      dst[1] = ((const float4*)p)[1];
    } else {
      float t[8];
#pragma unroll
      for (int j = 0; j < 8; ++j) t[j] = (gk + j < K) ? p[j] : 0.f;
      dst[0] = (float4){t[0], t[1], t[2], t[3]};
      dst[1] = (float4){t[4], t[5], t[6], t[7]};
    }
  };
  auto storeW = [&](const float4* src, int buf) {
    short4 s0, s1;
    s0.x = f2bf(src[0].x); s0.y = f2bf(src[0].y);
    s0.z = f2bf(src[0].z); s0.w = f2bf(src[0].w);
    s1.x = f2bf(src[1].x); s1.y = f2bf(src[1].y);
    s1.z = f2bf(src[1].z); s1.w = f2bf(src[1].w);
    short* q = &Wlds[buf][wrow * LDSW + (wq << 3)];
    *(short4*)q = s0;
    *(short4*)(q + 4) = s1;
  };
  auto loadA = [&](float4* dst, int k0) {
#pragma unroll
    for (int mi = 0; mi < 2; ++mi) {
#pragma unroll
      for (int kh = 0; kh < 2; ++kh) {
        int kk = k0 + (kh << 5) + (lg << 3);
        int m = (w << 5) + (mi << 4) + l15;
        const float* base; int kl, ld;
        if (kk < ksplit) { base = A0; kl = kk; ld = lda0; }
        else             { base = A1; kl = kk - ksplit; ld = lda1; }
        const float* p = base + (size_t)m * ld + kl;
        int idx = ((mi << 1) + kh) << 1;
        if (kk + 8 <= K) {
          dst[idx]     = ((const float4*)p)[0];
          dst[idx + 1] = ((const float4*)p)[1];
        } else {
          float t[8];
#pragma unroll
          for (int j = 0; j < 8; ++j) t[j] = (kk + j < K) ? p[j] : 0.f;
          dst[idx]     = (float4){t[0], t[1], t[2], t[3]};
          dst[idx + 1] = (float4){t[4], t[5], t[6], t[7]};
        }
      }
    }
  };
  auto convA = [&]() {
#pragma unroll
    for (int f = 0; f < 4; ++f) {
      float4 u = an[f << 1], v = an[(f << 1) + 1];
      bf16x8 r;
      r[0] = f2bf(u.x); r[1] = f2bf(u.y); r[2] = f2bf(u.z); r[3] = f2bf(u.w);
      r[4] = f2bf(v.x); r[5] = f2bf(v.y); r[6] = f2bf(v.z); r[7] = f2bf(v.w);
      ac[f >> 1][f & 1] = r;
    }
  };

  // ---- prologue ----
  loadW(wr[0], kbeg);            // tile 0
  loadA(an, kbeg);               // A tile 0
  storeW(wr[0], 0);              // waits tile-0 W
  if (nk > 1) loadW(wr[1], kbeg + 64);   // tile 1 in flight
  __syncthreads();

  for (int kt = 0; kt < nk; ++kt) {
    const int cur = kt & 1;
    const int k0 = kbeg + (kt << 6);
    convA();                                   // waits A(kt)
    if (kt + 1 < nk) {
      loadA(an, k0 + 64);                      // A(kt+1) in flight
      if (kt + 2 < nk) loadW(wr[cur], k0 + 128);  // W(kt+2) in flight
    }
    // MFMA on LDS buf[cur]
#pragma unroll
    for (int nj = 0; nj < 4; ++nj) {
      const short* bp = &Wlds[cur][((nj << 4) + l15) * LDSW + (lg << 3)];
      bf16x8 b0 = *(const bf16x8*)bp;
      bf16x8 b1 = *(const bf16x8*)(bp + 32);
      acc[0][nj] = __builtin_amdgcn_mfma_f32_16x16x32_bf16(ac[0][0], b0, acc[0][nj], 0, 0, 0);
      acc[1][nj] = __builtin_amdgcn_mfma_f32_16x16x32_bf16(ac[1][0], b0, acc[1][nj], 0, 0, 0);
      acc[0][nj] = __builtin_amdgcn_mfma_f32_16x16x32_bf16(ac[0][1], b1, acc[0][nj], 0, 0, 0);
      acc[1][nj] = __builtin_amdgcn_mfma_f32_16x16x32_bf16(ac[1][1], b1, acc[1][nj], 0, 0, 0);
    }
    if (kt + 1 < nk) {
      storeW(wr[cur ^ 1], cur ^ 1);            // waits W(kt+1); writes other buf
      __syncthreads();                         // buf ready for next step
    }
  }

  // ---- epilogue ----
  if (nchunks == 1) {
#pragma unroll
    for (int nj = 0; nj < 4; ++nj) {
      int gn = n0 + (nj << 4) + l15;
      if (gn >= N) continue;
      float bsum = 0.f;
      if (bias1) bsum += bias1[gn];
      if (bias2) bsum += bias2[gn];
#pragma unroll
      for (int mi = 0; mi < 2; ++mi) {
#pragma unroll
        for (int r = 0; r < 4; ++r) {
          int gm = (w << 5) + (mi << 4) + (lg << 2) + r;
          float v = acc[mi][nj][r] + bsum;
          if (do_relu) v = fmaxf(v, 0.f);
          C[(size_t)gm * ldc + gn] = v;
        }
      }
    }
  } else {
    float* Pb = P + (size_t)ks * 256 * (size_t)Np;
#pragma unroll
    for (int nj = 0; nj < 4; ++nj) {
      int gn = n0 + (nj << 4) + l15;
#pragma unroll
      for (int mi = 0; mi < 2; ++mi) {
#pragma unroll
        for (int r = 0; r < 4; ++r) {
          int gm = (w << 5) + (mi << 4) + (lg << 2) + r;
          Pb[(size_t)gm * Np + gn] = acc[mi][nj][r];
        }
      }
    }
  }
}

// ---------------- reduce partial slabs + bias + relu ----------------
__global__ void reduce_kernel(const float* __restrict__ P, int Np, int nchunks,
                              const float* __restrict__ bias1,
                              const float* __restrict__ bias2,
                              float* __restrict__ C, int ldc, int N, int relu) {
  int idx = blockIdx.x * 256 + threadIdx.x;
  int total = 256 * N;
  if (idx >= total) return;
  int m = idx / N;
  int n = idx - m * N;
  float s = 0.f;
  for (int ks = 0; ks < nchunks; ++ks)
    s += P[(size_t)ks * 256 * Np + (size_t)m * Np + n];
  if (bias1) s += bias1[n];
  if (bias2) s += bias2[n];
  if (relu) s = fmaxf(s, 0.f);
  C[(size_t)m * ldc + n] = s;
}

// ---------------- LSTM elementwise (h0 = c0 = 0) ----------------
__global__ void lstm_kernel(const float* __restrict__ gates,
                            float* __restrict__ zext) {
  int idx = blockIdx.x * blockDim.x + threadIdx.x;
  if (idx >= B_SZ * LSTM_N) return;
  int b = idx >> 9;
  int n = idx & 511;
  const float* g = gates + (size_t)b * (4 * LSTM_N);
  float gi = g[n];
  float gg = g[2 * LSTM_N + n];
  float go = g[3 * LSTM_N + n];
  float si = 1.f / (1.f + expf(-gi));
  float so = 1.f / (1.f + expf(-go));
  float c = si * tanhf(gg);
  float h = so * tanhf(c);
  zext[(size_t)b * 528 + n] = h;
}

// ---------------- softmax + gumbel-max categorical sample ----------------
__global__ void sample_kernel(const float* __restrict__ logits,    // [256,64]
                              const float* __restrict__ emb_dec_k, // [64,16]
                              float* __restrict__ zext,            // emb cols 512..527
                              int* __restrict__ act_out,
                              float* __restrict__ logp_out,
                              float* __restrict__ ent_out,
                              int k, int write_emb) {
  const int b = blockIdx.x;
  const int a = threadIdx.x;  // 0..63
  float logit = logits[b * ACT_N + a];

  float m = logit;
#pragma unroll
  for (int off = 32; off; off >>= 1) m = fmaxf(m, __shfl_xor(m, off));
  float e = expf(logit - m);
  float s = e;
#pragma unroll
  for (int off = 32; off; off >>= 1) s += __shfl_xor(s, off);
  float logp = logit - m - logf(s);

  float ent = -expf(logp) * logp;
#pragma unroll
  for (int off = 32; off; off >>= 1) ent += __shfl_xor(ent, off);

  uint32_t f0, f1;
  threefry2x32(0u, 42u, 0u, (uint32_t)k, f0, f1);
  uint32_t j = (uint32_t)(b * ACT_N + a);
  uint32_t o0, o1, bits;
  if (j < 8192u) {
    threefry2x32(f0, f1, j, j + 8192u, o0, o1);
    bits = o0;
  } else {
    threefry2x32(f0, f1, j - 8192u, j, o0, o1);
    bits = o1;
  }
  const float tiny = 1.17549435e-38f;
  float fu = __uint_as_float((bits >> 9) | 0x3f800000u) - 1.0f;
  float u = fmaxf(tiny, fu * (1.0f - tiny) + tiny);
  float gum = -logf(-logf(u));
  float pert = logit + gum;

  float bv = pert;
  int bi = a;
#pragma unroll
  for (int off = 32; off; off >>= 1) {
    float ov = __shfl_xor(bv, off);
    int oi = __shfl_xor(bi, off);
    if (ov > bv || (ov == bv && oi < bi)) { bv = ov; bi = oi; }
  }
  int act = bi;
  float lp_sel = __shfl(logp, act);

  if (a == 0) {
    act_out[b] = act;
    logp_out[b] = lp_sel;
    ent_out[b] = ent;
  }
  if (write_emb && a < 16) {
    zext[(size_t)b * 528 + 512 + a] = emb_dec_k[act * 16 + a];
  }
}

// ---------------- finalize: f32 outputs; parallel entropy reduce ----------------
// layout: action[1024] | entropy[1] | logp[256]
__global__ void finalize_kernel(const int* __restrict__ act,      // [4][256]
                                const float* __restrict__ logp_k, // [4][256]
                                const float* __restrict__ ent,    // [4][256]
                                float* __restrict__ out) {
  __shared__ float sred[4];
  int t = threadIdx.x;  // 0..255
#pragma unroll
  for (int k = 0; k < 4; ++k)
    out[t * 4 + k] = (float)act[k * 256 + t];
  float lp = 0.f;
#pragma unroll
  for (int k = 0; k < 4; ++k) lp += logp_k[k * 256 + t];
  out[1025 + t] = lp;

  float v = 0.f;
#pragma unroll
  for (int k = 0; k < 4; ++k) v += ent[k * 256 + t];
#pragma unroll
  for (int off = 32; off; off >>= 1) v += __shfl_xor(v, off);
  if ((t & 63) == 0) sred[t >> 6] = v;
  __syncthreads();
  if (t == 0) out[1024] = sred[0] + sred[1] + sred[2] + sred[3];
}

// ---------------- host launch ----------------
extern "C" void kernel_launch(void* const* d_in, const int* in_sizes, int n_in,
                              void* d_out, int out_size, void* d_ws, size_t ws_size,
                              hipStream_t stream) {
  float* out = (float*)d_out;
  char* out_bytes = (char*)d_out;

  auto sentinel = [&](int code) {
    hipMemsetAsync(out_bytes + 4096, code, 4, stream);
  };

  if (n_in < 25 || in_sizes[0] != B_SZ * 3 * 32 * 32 ||
      in_sizes[4] != FV_N * CIN_N || in_sizes[23] != LSTM_N * 528 ||
      in_sizes[9] <= 0 || in_sizes[9] > 8192 ||
      in_sizes[11] <= 0 || in_sizes[11] > 8192) {
    sentinel(0x42);
    return;
  }

  const float* actual = (const float*)d_in[0];
  const float* object = (const float*)d_in[1];
  const int* lastpos  = (const int*)d_in[2];
  const int* ep       = (const int*)d_in[3];
  const float* Wfe    = (const float*)d_in[4];
  const float* bfe    = (const float*)d_in[5];
  const float* emb_end= (const float*)d_in[6];
  const float* emb_ep = (const float*)d_in[7];
  const float* W1     = (const float*)d_in[8];
  const float* b1     = (const float*)d_in[9];
  const float* W2     = (const float*)d_in[10];
  const float* b2     = (const float*)d_in[11];
  const float* W3     = (const float*)d_in[12];
  const float* b3     = (const float*)d_in[13];
  const float* W_ih   = (const float*)d_in[14];
  const float* b_ih   = (const float*)d_in[16];
  const float* b_hh   = (const float*)d_in[17];
  const float* Wd1    = (const float*)d_in[18];
  const float* bd1    = (const float*)d_in[19];
  const float* Wd2    = (const float*)d_in[20];
  const float* bd2    = (const float*)d_in[21];
  const float* embdec = (const float*)d_in[22];
  const float* Wout   = (const float*)d_in[23];
  const float* bout   = (const float*)d_in[24];

  const int H1 = in_sizes[9];   // 2223
  const int H2 = in_sizes[11];  // 1067

  // ---- workspace layout ----
  const size_t base_floats = 3072 + (size_t)B_SZ * FEAT_N + (size_t)B_SZ * LD_H1;
  if (ws_size < base_floats * 4) {
    sentinel(0x43);
    return;
  }
  float* ws = (float*)d_ws;
  float* logpk = ws;
  float* entk  = ws + 1024;
  int*   actk  = (int*)(ws + 2048);
  float* R1 = ws + 3072;
  float* R2 = R1 + (size_t)B_SZ * FEAT_N;
  float* slab = R2 + (size_t)B_SZ * LD_H1;
  const size_t slab_floats = ws_size / 4 - base_floats;

  float* feats = R1;
  float* h1    = R2;
  float* h2    = R1;
  float* h3    = R2;
  float* gates = R1;
  float* zextA = R2;
  float* zextB = R2 + (size_t)B_SZ * 528;
  float* hm    = R1;
  float* logit = R1 + (size_t)B_SZ * 256;

  // gemm2 + optional reduce
  auto gemm = [&](const float* A0, int lda0, const float* A1, int lda1, int ksplit,
                  const float* W, int ldw, const float* bb1, const float* bb2,
                  float* C, int ldc, int N, int K, int relu, bool allow_split) {
    int nblk = (N + 63) / 64;
    int Np = nblk * 64;
    int chunks = 1, kc = ((K + 63) / 64) * 64;
    if (allow_split) {
      int target = 256 / nblk; if (target < 1) target = 1;
      int maxch = (K + 63) / 64;
      int ch = (target < maxch) ? target : maxch;
      size_t cap = slab_floats / ((size_t)256 * Np);
      if ((size_t)ch > cap) ch = (int)cap;
      if (ch < 1) ch = 1;
      kc = 64 * ((K + 64 * ch - 1) / (64 * ch));
      chunks = (K + kc - 1) / kc;
    }
    dim3 g(nblk, chunks);
    gemm2_kernel<<<g, dim3(512), 0, stream>>>(
        A0, lda0, A1, lda1, ksplit, W, ldw, bb1, bb2,
        C, ldc, slab, Np, N, K, relu, kc, chunks);
    if (chunks > 1) {
      int total = 256 * N;
      reduce_kernel<<<dim3((total + 255) / 256), dim3(256), 0, stream>>>(
          slab, Np, chunks, bb1, bb2, C, ldc, N, relu);
    }
  };

  // 1. fv = relu(concat(actual,objective) @ Wfe^T + bfe)
  gemm(actual, HALF_CIN, object, HALF_CIN, HALF_CIN,
       Wfe, CIN_N, bfe, nullptr, feats, FEAT_N, FV_N, CIN_N, 1, true);
  // 2. embeddings
  fill_embs_kernel<<<dim3(B_SZ), dim3(64), 0, stream>>>(
      lastpos, ep, emb_end, emb_ep, feats);
  // 3. h1 = relu(feats @ W1^T + b1)
  gemm(feats, FEAT_N, feats, 0, FEAT_N, W1, FEAT_N, b1, nullptr,
       h1, LD_H1, H1, FEAT_N, 1, true);
  // 4. h2 = relu(h1 @ W2^T + b2)
  gemm(h1, LD_H1, h1, 0, H1, W2, H1, b2, nullptr, h2, LD_H2, H2, H1, 1, true);
  // 5. h3 = relu(h2 @ W3^T + b3)
  gemm(h2, LD_H2, h2, 0, H2, W3, H2, b3, nullptr, h3, LSTM_N, LSTM_N, H2, 1, true);
  // 6. gates = h3 @ W_ih^T + b_ih + b_hh
  gemm(h3, LSTM_N, h3, 0, LSTM_N, W_ih, LSTM_N, b_ih, b_hh,
       gates, 4 * LSTM_N, 4 * LSTM_N, LSTM_N, 0, true);
  // 7. LSTM elementwise -> zextA[:, :512]
  lstm_kernel<<<dim3((B_SZ * LSTM_N + 255) / 256), dim3(256), 0, stream>>>(
      gates, zextA);

  // 8. autoregressive decoder (small GEMMs: direct path)
  float* zcur = zextA;
  float* znxt = zextB;
  for (int k = 0; k < 4; ++k) {
    const float* Wd1k = Wd1 + (size_t)k * 256 * LSTM_N;
    const float* bd1k = bd1 + (size_t)k * 256;
    const float* Wd2k = Wd2 + (size_t)k * ACT_N * 256;
    const float* bd2k = bd2 + (size_t)k * ACT_N;
    const float* embk = embdec + (size_t)k * ACT_N * 16;
    gemm(zcur, 528, zcur, 0, LSTM_N, Wd1k, LSTM_N, bd1k, nullptr,
         hm, 256, 256, LSTM_N, 1, false);
    gemm(hm, 256, hm, 0, 256, Wd2k, 256, bd2k, nullptr,
         logit, ACT_N, ACT_N, 256, 0, false);
    sample_kernel<<<dim3(B_SZ), dim3(64), 0, stream>>>(
        logit, embk, zcur, actk + k * B_SZ, logpk + k * B_SZ,
        entk + k * B_SZ, k, (k < 3) ? 1 : 0);
    if (k < 3) {
      gemm(zcur, 528, zcur, 0, 528, Wout, 528, bout, nullptr,
           znxt, 528, LSTM_N, 528, 1, false);
      float* t = zcur; zcur = znxt; znxt = t;
    }
  }

  // 9. pack outputs (f32)
  finalize_kernel<<<dim3(1), dim3(256), 0, stream>>>(actk, logpk, entk, out);
}

// Round 7
// 313.590 us; speedup vs baseline: 9.3464x; 1.5004x over previous
//
#include <hip/hip_runtime.h>
#include <hip/hip_bf16.h>
#include <stdint.h>

// ---------------- constants ----------------
#define B_SZ   256
#define LSTM_N 512
#define FEAT_N 4632
#define FV_N   4608
#define CIN_N  6144
#define HALF_CIN 3072
#define ACT_N  64
#define LDSW   72
#define LD_FEAT 4672   // 64-mult >= 4632
#define LD_ZEXT 576    // 64-mult >= 528

typedef __attribute__((ext_vector_type(8))) short bf16x8;
typedef __attribute__((ext_vector_type(4))) float f32x4;

__device__ __forceinline__ short f2bf(float f) {
  uint32_t u = __float_as_uint(f);
  u += 0x7FFFu + ((u >> 16) & 1u);
  return (short)(u >> 16);
}
__device__ __forceinline__ float bf2f(short s) {
  return __uint_as_float(((uint32_t)(uint16_t)s) << 16);
}

// ---------------- threefry2x32 (matches jax) ----------------
__device__ __forceinline__ uint32_t rotl32(uint32_t x, int r) {
  return (x << r) | (x >> (32 - r));
}
__device__ __forceinline__ void threefry2x32(uint32_t k0, uint32_t k1,
                                             uint32_t x0, uint32_t x1,
                                             uint32_t& o0, uint32_t& o1) {
  uint32_t k2 = k0 ^ k1 ^ 0x1BD11BDAu;
  x0 += k0; x1 += k1;
  x0 += x1; x1 = rotl32(x1, 13); x1 ^= x0;
  x0 += x1; x1 = rotl32(x1, 15); x1 ^= x0;
  x0 += x1; x1 = rotl32(x1, 26); x1 ^= x0;
  x0 += x1; x1 = rotl32(x1,  6); x1 ^= x0;
  x0 += k1; x1 += k2 + 1u;
  x0 += x1; x1 = rotl32(x1, 17); x1 ^= x0;
  x0 += x1; x1 = rotl32(x1, 29); x1 ^= x0;
  x0 += x1; x1 = rotl32(x1, 16); x1 ^= x0;
  x0 += x1; x1 = rotl32(x1, 24); x1 ^= x0;
  x0 += k2; x1 += k0 + 2u;
  x0 += x1; x1 = rotl32(x1, 13); x1 ^= x0;
  x0 += x1; x1 = rotl32(x1, 15); x1 ^= x0;
  x0 += x1; x1 = rotl32(x1, 26); x1 ^= x0;
  x0 += x1; x1 = rotl32(x1,  6); x1 ^= x0;
  x0 += k0; x1 += k1 + 3u;
  x0 += x1; x1 = rotl32(x1, 17); x1 ^= x0;
  x0 += x1; x1 = rotl32(x1, 29); x1 ^= x0;
  x0 += x1; x1 = rotl32(x1, 16); x1 ^= x0;
  x0 += x1; x1 = rotl32(x1, 24); x1 ^= x0;
  x0 += k1; x1 += k2 + 4u;
  x0 += x1; x1 = rotl32(x1, 13); x1 ^= x0;
  x0 += x1; x1 = rotl32(x1, 15); x1 ^= x0;
  x0 += x1; x1 = rotl32(x1, 26); x1 ^= x0;
  x0 += x1; x1 = rotl32(x1,  6); x1 ^= x0;
  x0 += k2; x1 += k0 + 5u;
  o0 = x0; o1 = x1;
}

// ---------------- concat canvases + cvt to bf16: xb[256][6144] ----------------
__global__ void concat_cvt_kernel(const float* __restrict__ act,
                                  const float* __restrict__ obj,
                                  short* __restrict__ xb) {
  int idx = blockIdx.x * 256 + threadIdx.x;      // 256*768 threads
  if (idx >= B_SZ * 768) return;
  int row = idx / 768;
  int c8 = (idx - row * 768) * 8;
  const float* src = (c8 < HALF_CIN) ? (act + (size_t)row * HALF_CIN + c8)
                                     : (obj + (size_t)row * HALF_CIN + (c8 - HALF_CIN));
  float4 u = ((const float4*)src)[0];
  float4 v = ((const float4*)src)[1];
  bf16x8 r;
  r[0]=f2bf(u.x); r[1]=f2bf(u.y); r[2]=f2bf(u.z); r[3]=f2bf(u.w);
  r[4]=f2bf(v.x); r[5]=f2bf(v.y); r[6]=f2bf(v.z); r[7]=f2bf(v.w);
  *(bf16x8*)&xb[(size_t)row * CIN_N + c8] = r;
}

// ---------------- embeddings into feats cols [4608,4632) + zero pad [4632,4672) ----------------
__global__ void fill_embs_kernel(const int* __restrict__ lastpos,
                                 const int* __restrict__ ep,
                                 const float* __restrict__ emb_end,
                                 const float* __restrict__ emb_ep,
                                 short* __restrict__ feats) {
  int b = blockIdx.x;
  int t = threadIdx.x;   // 0..63
  short* row = feats + (size_t)b * LD_FEAT;
  if (t < 16) {
    row[FV_N + t] = f2bf(emb_end[lastpos[b] * 16 + t]);
  } else if (t < 24) {
    row[FV_N + 16 + (t - 16)] = f2bf(emb_ep[ep[b] * 8 + (t - 16)]);
  } else {
    row[FV_N + t] = 0;   // cols 4632..4671
  }
}

// ---------------- bf16 MFMA GEMM v3 ----------------
// C[256,N] = act(A_bf16[256,K] @ W_f32[N,K]^T + b1 + b2)
// tile 256m x 64n, 8 waves; K chunked (grid.y); out: direct bf16/f32 or bf16 slab.
__global__ __launch_bounds__(512) void gemm3_kernel(
    const short* __restrict__ A, int ldab,
    const float* __restrict__ W, int ldw,
    const float* __restrict__ bias1, const float* __restrict__ bias2,
    void* __restrict__ Cout, int ldc,
    short* __restrict__ P,
    int N, int K, int do_relu, int mode_f32, int kc, int nchunks) {
  __shared__ short Wlds[2][64 * LDSW];

  const int tid = threadIdx.x;
  const int w = tid >> 6, l = tid & 63, l15 = l & 15, lg = l >> 4;
  const int n0 = blockIdx.x * 64;
  const int Np = gridDim.x * 64;
  const int ks = blockIdx.y;
  const int kbeg = ks * kc;
  const int kend = (kbeg + kc < K) ? (kbeg + kc) : K;
  const int nk = (kend - kbeg + 63) >> 6;
  const bool wfast = ((ldw & 3) == 0);

  f32x4 acc[2][4];
#pragma unroll
  for (int i = 0; i < 2; ++i)
#pragma unroll
    for (int j = 0; j < 4; ++j) acc[i][j] = (f32x4){0.f, 0.f, 0.f, 0.f};

  const int wrow = tid >> 3, wq = tid & 7;

  auto loadW = [&](float4* dst, int k0) {
    int gn = n0 + wrow; if (gn >= N) gn = N - 1;
    int gk = k0 + (wq << 3);
    const float* p = W + (size_t)gn * ldw + gk;
    if (wfast && (k0 + 64 <= K)) {
      dst[0] = ((const float4*)p)[0];
      dst[1] = ((const float4*)p)[1];
    } else {
      float t[8];
#pragma unroll
      for (int j = 0; j < 8; ++j) t[j] = (gk + j < K) ? p[j] : 0.f;
      dst[0] = (float4){t[0], t[1], t[2], t[3]};
      dst[1] = (float4){t[4], t[5], t[6], t[7]};
    }
  };
  auto storeW = [&](const float4* src, int buf) {
    short4 s0, s1;
    s0.x = f2bf(src[0].x); s0.y = f2bf(src[0].y);
    s0.z = f2bf(src[0].z); s0.w = f2bf(src[0].w);
    s1.x = f2bf(src[1].x); s1.y = f2bf(src[1].y);
    s1.z = f2bf(src[1].z); s1.w = f2bf(src[1].w);
    short* q = &Wlds[buf][wrow * LDSW + (wq << 3)];
    *(short4*)q = s0;
    *(short4*)(q + 4) = s1;
  };
  auto loadA = [&](bf16x8* dst, int k0) {
#pragma unroll
    for (int mi = 0; mi < 2; ++mi)
#pragma unroll
      for (int kh = 0; kh < 2; ++kh) {
        int m = (w << 5) + (mi << 4) + l15;
        int kk = k0 + (kh << 5) + (lg << 3);
        dst[(mi << 1) + kh] = *(const bf16x8*)&A[(size_t)m * ldab + kk];
      }
  };

#define MFMA_STEP(ACUR, BUF)                                                        \
  {                                                                                 \
    _Pragma("unroll")                                                               \
    for (int nj = 0; nj < 4; ++nj) {                                                \
      const short* bp = &Wlds[BUF][((nj << 4) + l15) * LDSW + (lg << 3)];           \
      bf16x8 b0 = *(const bf16x8*)bp;                                               \
      bf16x8 b1 = *(const bf16x8*)(bp + 32);                                        \
      acc[0][nj] = __builtin_amdgcn_mfma_f32_16x16x32_bf16(ACUR[0], b0, acc[0][nj], 0, 0, 0); \
      acc[1][nj] = __builtin_amdgcn_mfma_f32_16x16x32_bf16(ACUR[2], b0, acc[1][nj], 0, 0, 0); \
      acc[0][nj] = __builtin_amdgcn_mfma_f32_16x16x32_bf16(ACUR[1], b1, acc[0][nj], 0, 0, 0); \
      acc[1][nj] = __builtin_amdgcn_mfma_f32_16x16x32_bf16(ACUR[3], b1, acc[1][nj], 0, 0, 0); \
    }                                                                               \
  }

#define STEP(KT, ACUR, ANXT, WCUR, WNXT, BUF, BUFN)          \
  {                                                          \
    if ((KT) + 1 < nk) loadA(ANXT, kbeg + (((KT) + 1) << 6));\
    if ((KT) + 2 < nk) loadW(WCUR, kbeg + (((KT) + 2) << 6));\
    MFMA_STEP(ACUR, BUF);                                    \
    if ((KT) + 1 < nk) { storeW(WNXT, BUFN); __syncthreads(); } \
  }

  bf16x8 a0[4], a1[4];
  float4 wr0[2], wr1[2];

  loadW(wr0, kbeg);
  loadA(a0, kbeg);
  storeW(wr0, 0);
  if (nk > 1) loadW(wr1, kbeg + 64);
  __syncthreads();

  for (int kt = 0; kt < nk; kt += 2) {
    STEP(kt, a0, a1, wr0, wr1, 0, 1);
    if (kt + 1 < nk) STEP(kt + 1, a1, a0, wr1, wr0, 1, 0);
  }

  // ---- epilogue ----
  if (nchunks == 1) {
#pragma unroll
    for (int nj = 0; nj < 4; ++nj) {
      int gn = n0 + (nj << 4) + l15;
      float bsum = 0.f;
      if (gn < N) {
        if (bias1) bsum += bias1[gn];
        if (bias2) bsum += bias2[gn];
      }
#pragma unroll
      for (int mi = 0; mi < 2; ++mi)
#pragma unroll
        for (int r = 0; r < 4; ++r) {
          int gm = (w << 5) + (mi << 4) + (lg << 2) + r;
          float v = (gn < N) ? (acc[mi][nj][r] + bsum) : 0.f;
          if (do_relu) v = fmaxf(v, 0.f);
          if (mode_f32) ((float*)Cout)[(size_t)gm * ldc + gn] = v;
          else          ((short*)Cout)[(size_t)gm * ldc + gn] = f2bf(v);
        }
    }
  } else {
    short* Pb = P + (size_t)ks * 256 * Np;
#pragma unroll
    for (int nj = 0; nj < 4; ++nj) {
      int gn = n0 + (nj << 4) + l15;
#pragma unroll
      for (int mi = 0; mi < 2; ++mi)
#pragma unroll
        for (int r = 0; r < 4; ++r) {
          int gm = (w << 5) + (mi << 4) + (lg << 2) + r;
          Pb[(size_t)gm * Np + gn] = f2bf(acc[mi][nj][r]);
        }
    }
  }
#undef STEP
#undef MFMA_STEP
}

// ---------------- reduce bf16 slab -> bf16/f32 out (+bias +relu, zero pads) ----------------
__global__ void reduce_kernel(const short* __restrict__ P, int Np, int nchunks,
                              const float* __restrict__ bias1,
                              const float* __restrict__ bias2,
                              void* __restrict__ out, int ldc, int N,
                              int relu, int mode_f32) {
  int npack = Np >> 3;
  int idx = blockIdx.x * 256 + threadIdx.x;
  if (idx >= 256 * npack) return;
  int m = idx / npack;
  int n8 = (idx - m * npack) << 3;
  float s[8] = {0.f, 0.f, 0.f, 0.f, 0.f, 0.f, 0.f, 0.f};
  for (int ks = 0; ks < nchunks; ++ks) {
    bf16x8 v = *(const bf16x8*)&P[(size_t)ks * 256 * Np + (size_t)m * Np + n8];
#pragma unroll
    for (int j = 0; j < 8; ++j) s[j] += bf2f(v[j]);
  }
#pragma unroll
  for (int j = 0; j < 8; ++j) {
    int n = n8 + j;
    float r = 0.f;
    if (n < N) {
      r = s[j];
      if (bias1) r += bias1[n];
      if (bias2) r += bias2[n];
      if (relu) r = fmaxf(r, 0.f);
    }
    s[j] = r;
  }
  if (mode_f32) {
    float* o = (float*)out + (size_t)m * ldc + n8;
#pragma unroll
    for (int j = 0; j < 8; ++j) o[j] = s[j];
  } else {
    bf16x8 r;
#pragma unroll
    for (int j = 0; j < 8; ++j) r[j] = f2bf(s[j]);
    *(bf16x8*)((short*)out + (size_t)m * ldc + n8) = r;
  }
}

// ---------------- LSTM elementwise (h0 = c0 = 0) -> zext bf16 ----------------
__global__ void lstm_kernel(const float* __restrict__ gates,
                            short* __restrict__ zext) {
  int idx = blockIdx.x * blockDim.x + threadIdx.x;
  if (idx >= B_SZ * LSTM_N) return;
  int b = idx >> 9;
  int n = idx & 511;
  const float* g = gates + (size_t)b * (4 * LSTM_N);
  float gi = g[n];
  float gg = g[2 * LSTM_N + n];
  float go = g[3 * LSTM_N + n];
  float si = 1.f / (1.f + expf(-gi));
  float so = 1.f / (1.f + expf(-go));
  float c = si * tanhf(gg);
  float h = so * tanhf(c);
  zext[(size_t)b * LD_ZEXT + n] = f2bf(h);
}

// ---------------- softmax + gumbel-max categorical sample ----------------
__global__ void sample_kernel(const float* __restrict__ logits,    // [256,64]
                              const float* __restrict__ emb_dec_k, // [64,16]
                              short* __restrict__ zext,            // bf16, cols 512.. + zero pads
                              int* __restrict__ act_out,
                              float* __restrict__ logp_out,
                              float* __restrict__ ent_out,
                              int k, int write_emb) {
  const int b = blockIdx.x;
  const int a = threadIdx.x;  // 0..63
  float logit = logits[b * ACT_N + a];

  float m = logit;
#pragma unroll
  for (int off = 32; off; off >>= 1) m = fmaxf(m, __shfl_xor(m, off));
  float e = expf(logit - m);
  float s = e;
#pragma unroll
  for (int off = 32; off; off >>= 1) s += __shfl_xor(s, off);
  float logp = logit - m - logf(s);

  float ent = -expf(logp) * logp;
#pragma unroll
  for (int off = 32; off; off >>= 1) ent += __shfl_xor(ent, off);

  uint32_t f0, f1;
  threefry2x32(0u, 42u, 0u, (uint32_t)k, f0, f1);
  uint32_t j = (uint32_t)(b * ACT_N + a);
  uint32_t o0, o1, bits;
  if (j < 8192u) {
    threefry2x32(f0, f1, j, j + 8192u, o0, o1);
    bits = o0;
  } else {
    threefry2x32(f0, f1, j - 8192u, j, o0, o1);
    bits = o1;
  }
  const float tiny = 1.17549435e-38f;
  float fu = __uint_as_float((bits >> 9) | 0x3f800000u) - 1.0f;
  float u = fmaxf(tiny, fu * (1.0f - tiny) + tiny);
  float gum = -logf(-logf(u));
  float pert = logit + gum;

  float bv = pert;
  int bi = a;
#pragma unroll
  for (int off = 32; off; off >>= 1) {
    float ov = __shfl_xor(bv, off);
    int oi = __shfl_xor(bi, off);
    if (ov > bv || (ov == bv && oi < bi)) { bv = ov; bi = oi; }
  }
  int act = bi;
  float lp_sel = __shfl(logp, act);

  if (a == 0) {
    act_out[b] = act;
    logp_out[b] = lp_sel;
    ent_out[b] = ent;
  }
  if (write_emb) {
    if (a < 16) zext[(size_t)b * LD_ZEXT + 512 + a] = f2bf(emb_dec_k[act * 16 + a]);
    else        zext[(size_t)b * LD_ZEXT + 512 + a] = 0;  // cols 528..575
  }
}

// ---------------- finalize (f32 out): action[1024] | entropy[1] | logp[256] ----------------
__global__ void finalize_kernel(const int* __restrict__ act,
                                const float* __restrict__ logp_k,
                                const float* __restrict__ ent,
                                float* __restrict__ out) {
  __shared__ float sred[4];
  int t = threadIdx.x;  // 0..255
#pragma unroll
  for (int k = 0; k < 4; ++k)
    out[t * 4 + k] = (float)act[k * 256 + t];
  float lp = 0.f;
#pragma unroll
  for (int k = 0; k < 4; ++k) lp += logp_k[k * 256 + t];
  out[1025 + t] = lp;

  float v = 0.f;
#pragma unroll
  for (int k = 0; k < 4; ++k) v += ent[k * 256 + t];
#pragma unroll
  for (int off = 32; off; off >>= 1) v += __shfl_xor(v, off);
  if ((t & 63) == 0) sred[t >> 6] = v;
  __syncthreads();
  if (t == 0) out[1024] = sred[0] + sred[1] + sred[2] + sred[3];
}

// ---------------- host launch ----------------
extern "C" void kernel_launch(void* const* d_in, const int* in_sizes, int n_in,
                              void* d_out, int out_size, void* d_ws, size_t ws_size,
                              hipStream_t stream) {
  float* out = (float*)d_out;
  char* out_bytes = (char*)d_out;
  auto sentinel = [&](int code) { hipMemsetAsync(out_bytes + 4096, code, 4, stream); };

  if (n_in < 25 || in_sizes[0] != B_SZ * 3 * 32 * 32 ||
      in_sizes[4] != FV_N * CIN_N || in_sizes[23] != LSTM_N * 528 ||
      in_sizes[9] <= 0 || in_sizes[9] > 8192 ||
      in_sizes[11] <= 0 || in_sizes[11] > 8192) {
    sentinel(0x42);
    return;
  }

  const float* actual = (const float*)d_in[0];
  const float* object = (const float*)d_in[1];
  const int* lastpos  = (const int*)d_in[2];
  const int* ep       = (const int*)d_in[3];
  const float* Wfe    = (const float*)d_in[4];
  const float* bfe    = (const float*)d_in[5];
  const float* emb_end= (const float*)d_in[6];
  const float* emb_ep = (const float*)d_in[7];
  const float* W1     = (const float*)d_in[8];
  const float* b1     = (const float*)d_in[9];
  const float* W2     = (const float*)d_in[10];
  const float* b2     = (const float*)d_in[11];
  const float* W3     = (const float*)d_in[12];
  const float* b3     = (const float*)d_in[13];
  const float* W_ih   = (const float*)d_in[14];
  const float* b_ih   = (const float*)d_in[16];
  const float* b_hh   = (const float*)d_in[17];
  const float* Wd1    = (const float*)d_in[18];
  const float* bd1    = (const float*)d_in[19];
  const float* Wd2    = (const float*)d_in[20];
  const float* bd2    = (const float*)d_in[21];
  const float* embdec = (const float*)d_in[22];
  const float* Wout   = (const float*)d_in[23];
  const float* bout   = (const float*)d_in[24];

  const int H1 = in_sizes[9];
  const int H2 = in_sizes[11];
  const int ldh1 = 64 * ((H1 + 63) / 64);   // 2240
  const int ldh2 = 64 * ((H2 + 63) / 64);   // 1088

  // ---- workspace layout (bytes) ----
  char* wsb = (char*)d_ws;
  size_t off = 0;
  auto alloc = [&](size_t bytes) {
    char* p = wsb + off;
    off += (bytes + 255) & ~(size_t)255;
    return p;
  };
  float* logpk = (float*)alloc(1024 * 4);
  float* entk  = (float*)alloc(1024 * 4);
  int*   actk  = (int*)alloc(1024 * 4);
  short* xb    = (short*)alloc((size_t)B_SZ * CIN_N * 2);
  short* feats = (short*)alloc((size_t)B_SZ * LD_FEAT * 2);
  short* h1    = (short*)alloc((size_t)B_SZ * ldh1 * 2);
  short* h2    = (short*)alloc((size_t)B_SZ * ldh2 * 2);
  short* h3    = (short*)alloc((size_t)B_SZ * 512 * 2);
  float* gates = (float*)alloc((size_t)B_SZ * 2048 * 4);
  short* zextA = (short*)alloc((size_t)B_SZ * LD_ZEXT * 2);
  short* zextB = (short*)alloc((size_t)B_SZ * LD_ZEXT * 2);
  short* hm    = (short*)alloc((size_t)B_SZ * 256 * 2);
  float* logit = (float*)alloc((size_t)B_SZ * 64 * 4);
  if (off + (1 << 20) > ws_size) {   // need at least fixed + 1MB slab headroom
    sentinel(0x43);
    return;
  }
  short* slab = (short*)(wsb + off);
  const size_t slab_bytes = ws_size - off;

  auto gemm = [&](const short* A, int ldab, const float* W, int ldw,
                  const float* bb1, const float* bb2,
                  void* C, int ldc, int N, int K, int relu, int mode_f32,
                  bool split) {
    int nblk = (N + 63) / 64;
    int Np = nblk * 64;
    int chunks = 1;
    int kc = 64 * ((K + 63) / 64);
    if (split) {
      int by_grid = (768 + nblk - 1) / nblk;
      int by_traffic = K / 320; if (by_traffic < 2) by_traffic = 2;
      int c = (by_grid < by_traffic) ? by_grid : by_traffic;
      int maxch = (K + 63) / 64; if (c > maxch) c = maxch;
      size_t cap = slab_bytes / ((size_t)256 * Np * 2);
      if ((size_t)c > cap) c = (int)cap;
      if (c < 1) c = 1;
      kc = 64 * ((K + 64 * c - 1) / (64 * c));
      chunks = (K + kc - 1) / kc;
    }
    dim3 g(nblk, chunks);
    gemm3_kernel<<<g, dim3(512), 0, stream>>>(
        A, ldab, W, ldw, bb1, bb2, C, ldc, slab, N, K, relu, mode_f32, kc, chunks);
    if (chunks > 1) {
      int npack = Np >> 3;
      reduce_kernel<<<dim3((256 * npack + 255) / 256), dim3(256), 0, stream>>>(
          slab, Np, chunks, bb1, bb2, C, ldc, N, relu, mode_f32);
    }
  };

  // 0. concat + cvt canvases -> xb bf16
  concat_cvt_kernel<<<dim3(768), dim3(256), 0, stream>>>(actual, object, xb);
  // 1. feats[:, :4608] = relu(xb @ Wfe^T + bfe)
  gemm(xb, CIN_N, Wfe, CIN_N, bfe, nullptr, feats, LD_FEAT, FV_N, CIN_N, 1, 0, true);
  // 2. embeddings + zero pad
  fill_embs_kernel<<<dim3(B_SZ), dim3(64), 0, stream>>>(lastpos, ep, emb_end, emb_ep, feats);
  // 3. h1 = relu(feats @ W1^T + b1)
  gemm(feats, LD_FEAT, W1, FEAT_N, b1, nullptr, h1, ldh1, H1, FEAT_N, 1, 0, true);
  // 4. h2 = relu(h1 @ W2^T + b2)
  gemm(h1, ldh1, W2, H1, b2, nullptr, h2, ldh2, H2, H1, 1, 0, true);
  // 5. h3 = relu(h2 @ W3^T + b3)
  gemm(h2, ldh2, W3, H2, b3, nullptr, h3, 512, LSTM_N, H2, 1, 0, true);
  // 6. gates = h3 @ W_ih^T + b_ih + b_hh   (f32 out)
  gemm(h3, 512, W_ih, LSTM_N, b_ih, b_hh, gates, 2048, 4 * LSTM_N, LSTM_N, 0, 1, true);
  // 7. LSTM -> zextA[:, :512] bf16
  lstm_kernel<<<dim3((B_SZ * LSTM_N + 255) / 256), dim3(256), 0, stream>>>(gates, zextA);

  // 8. autoregressive decoder (direct GEMMs)
  short* zcur = zextA;
  short* znxt = zextB;
  for (int k = 0; k < 4; ++k) {
    const float* Wd1k = Wd1 + (size_t)k * 256 * LSTM_N;
    const float* bd1k = bd1 + (size_t)k * 256;
    const float* Wd2k = Wd2 + (size_t)k * ACT_N * 256;
    const float* bd2k = bd2 + (size_t)k * ACT_N;
    const float* embk = embdec + (size_t)k * ACT_N * 16;
    gemm(zcur, LD_ZEXT, Wd1k, LSTM_N, bd1k, nullptr, hm, 256, 256, LSTM_N, 1, 0, false);
    gemm(hm, 256, Wd2k, 256, bd2k, nullptr, logit, 64, ACT_N, 256, 0, 1, false);
    sample_kernel<<<dim3(B_SZ), dim3(64), 0, stream>>>(
        logit, embk, zcur, actk + k * B_SZ, logpk + k * B_SZ,
        entk + k * B_SZ, k, (k < 3) ? 1 : 0);
    if (k < 3) {
      gemm(zcur, LD_ZEXT, Wout, 528, bout, nullptr, znxt, LD_ZEXT, LSTM_N, 528, 1, 0, false);
      short* t = zcur; zcur = znxt; znxt = t;
    }
  }

  // 9. outputs
  finalize_kernel<<<dim3(1), dim3(256), 0, stream>>>(actk, logpk, entk, out);
}